// Round 1
// baseline (1259.023 us; speedup 1.0000x reference)
//
#include <hip/hip_runtime.h>
#include <stdint.h>

#define D 64
#define DIN 192
#define RDIM 9
#define TILE 64          // edges per tile
#define IST 200          // inp LDS row stride in bf16 elems (400B, multiple of 16B, 2-way banks only)
#define HST 72           // h/g LDS row stride in bf16 elems (144B, multiple of 16B)

typedef short bf16x8 __attribute__((ext_vector_type(8)));
typedef float f32x4 __attribute__((ext_vector_type(4)));

__device__ __forceinline__ unsigned short f2bf(float f) {
    union { float f; unsigned int u; } v; v.f = f;
    unsigned int r = (v.u + 0x7fffu + ((v.u >> 16) & 1u)) >> 16;  // RNE
    return (unsigned short)r;
}
__device__ __forceinline__ float bf2f(unsigned short h) {
    union { unsigned int u; float f; } v; v.u = ((unsigned int)h) << 16;
    return v.f;
}
__device__ __forceinline__ float sigmoidf_(float x) { return 1.0f / (1.0f + __expf(-x)); }
__device__ __forceinline__ float siluf_(float x) { return x * sigmoidf_(x); }
__device__ __forceinline__ f32x4 splat4(float v) { f32x4 r; r[0] = v; r[1] = v; r[2] = v; r[3] = v; return r; }

// MODE 0: edge update -> writes new_edge = edge + eu to out_edge
// MODE 1: node messages -> atomicAdd msg into agg[dst]
template<int MODE>
__global__ __launch_bounds__(256) void mlp_kernel(
    const float* __restrict__ node_f,   // [N,64]
    const float* __restrict__ mid_f,    // [E,64]: edge_features (MODE0) or new_edge (MODE1)
    const int*   __restrict__ src,
    const int*   __restrict__ dst,
    const float* __restrict__ rbf,      // [E,9]
    const float* __restrict__ shw,      // [E,64] shared_{edge|node}_weights
    const float* __restrict__ W1,  const float* __restrict__ b1,
    const float* __restrict__ W2,  const float* __restrict__ b2,
    const float* __restrict__ gW1, const float* __restrict__ gb1,
    const float* __restrict__ gW2, const float* __restrict__ gb2,
    const float* __restrict__ wfW,      // [9,64]
    float* __restrict__ out_edge,       // MODE0 target
    float* __restrict__ agg,            // MODE1 target
    int E, int ntiles)
{
    __shared__ __align__(16) unsigned short s_inp[TILE * IST];
    __shared__ __align__(16) unsigned short s_h[TILE * HST];
    __shared__ __align__(16) unsigned short s_g[TILE * HST];
    __shared__ float s_rbf[TILE * 10];

    const int tid  = threadIdx.x;
    const int lane = tid & 63;
    const int wave = tid >> 6;
    const int l15  = lane & 15;
    const int quad = lane >> 4;
    const int n    = wave * 16 + l15;   // output column this lane owns

    // ---- per-wave weight B-fragments in registers (bf16) ----
    bf16x8 w1f[6], gw1f[6], w2f[2], gw2f[2];
#pragma unroll
    for (int kt = 0; kt < 6; ++kt) {
#pragma unroll
        for (int j = 0; j < 8; ++j) {
            int k = kt * 32 + quad * 8 + j;
            w1f[kt][j]  = (short)f2bf(W1[k * 64 + n]);
            gw1f[kt][j] = (short)f2bf(gW1[k * 64 + n]);
        }
    }
#pragma unroll
    for (int kt = 0; kt < 2; ++kt) {
#pragma unroll
        for (int j = 0; j < 8; ++j) {
            int k = kt * 32 + quad * 8 + j;
            w2f[kt][j]  = (short)f2bf(W2[k * 64 + n]);
            gw2f[kt][j] = (short)f2bf(gW2[k * 64 + n]);
        }
    }
    float wfw[RDIM];
#pragma unroll
    for (int r = 0; r < RDIM; ++r) wfw[r] = wfW[r * 64 + n];
    const float b1n = b1[n], b2n = b2[n], gb1n = gb1[n], gb2n = gb2[n];

    for (int tile = blockIdx.x; tile < ntiles; tile += gridDim.x) {
        const int e0 = tile * TILE;
        __syncthreads();   // previous tile's LDS consumers done

        // ---- stage inputs: [xi | mid | xj] as bf16, plus rbf tile ----
        {
            const int col = tid & 63;
            const int eg  = tid >> 6;
#pragma unroll 4
            for (int i = 0; i < 16; ++i) {
                int el = i * 4 + eg;
                int e  = e0 + el;
                int ec = e < E ? e : E - 1;
                int si = src[ec], di = dst[ec];
                float xi = node_f[si * 64 + col];
                float xj = node_f[di * 64 + col];
                float mf = mid_f[ec * 64 + col];
                s_inp[el * IST +       col] = f2bf(xi);
                s_inp[el * IST +  64 + col] = f2bf(mf);
                s_inp[el * IST + 128 + col] = f2bf(xj);
            }
            for (int idx = tid; idx < TILE * RDIM; idx += 256) {
                int gi = e0 * RDIM + idx;
                float v = (gi < E * RDIM) ? rbf[gi] : 0.0f;
                s_rbf[(idx / RDIM) * 10 + (idx % RDIM)] = v;
            }
        }
        __syncthreads();

        // ---- stage 1: a1 = inp@W1+b1 ; ag1 = inp@gW1+gb1 ----
        f32x4 acc_h[4], acc_g[4];
#pragma unroll
        for (int mt = 0; mt < 4; ++mt) { acc_h[mt] = splat4(b1n); acc_g[mt] = splat4(gb1n); }
#pragma unroll
        for (int kt = 0; kt < 6; ++kt) {
#pragma unroll
            for (int mt = 0; mt < 4; ++mt) {
                const bf16x8 a = *(const bf16x8*)&s_inp[(mt * 16 + l15) * IST + kt * 32 + quad * 8];
                acc_h[mt] = __builtin_amdgcn_mfma_f32_16x16x32_bf16(a, w1f[kt],  acc_h[mt], 0, 0, 0);
                acc_g[mt] = __builtin_amdgcn_mfma_f32_16x16x32_bf16(a, gw1f[kt], acc_g[mt], 0, 0, 0);
            }
        }
        // silu, write h/g tiles to LDS (D layout: row = quad*4+r, col = n)
#pragma unroll
        for (int mt = 0; mt < 4; ++mt) {
#pragma unroll
            for (int r = 0; r < 4; ++r) {
                int row = mt * 16 + quad * 4 + r;
                s_h[row * HST + n] = f2bf(siluf_(acc_h[mt][r]));
                s_g[row * HST + n] = f2bf(siluf_(acc_g[mt][r]));
            }
        }
        __syncthreads();

        // ---- stage 2: h2 = h@W2+b2 ; g2 = g@gW2+gb2 ----
        f32x4 acc2_h[4], acc2_g[4];
#pragma unroll
        for (int mt = 0; mt < 4; ++mt) { acc2_h[mt] = splat4(b2n); acc2_g[mt] = splat4(gb2n); }
#pragma unroll
        for (int kt = 0; kt < 2; ++kt) {
#pragma unroll
            for (int mt = 0; mt < 4; ++mt) {
                const bf16x8 ah = *(const bf16x8*)&s_h[(mt * 16 + l15) * HST + kt * 32 + quad * 8];
                acc2_h[mt] = __builtin_amdgcn_mfma_f32_16x16x32_bf16(ah, w2f[kt], acc2_h[mt], 0, 0, 0);
                const bf16x8 ag = *(const bf16x8*)&s_g[(mt * 16 + l15) * HST + kt * 32 + quad * 8];
                acc2_g[mt] = __builtin_amdgcn_mfma_f32_16x16x32_bf16(ag, gw2f[kt], acc2_g[mt], 0, 0, 0);
            }
        }

        // ---- epilogue ----
#pragma unroll
        for (int mt = 0; mt < 4; ++mt) {
#pragma unroll
            for (int r = 0; r < 4; ++r) {
                int el = mt * 16 + quad * 4 + r;
                int e  = e0 + el;
                if (e >= E) continue;
                float h2 = siluf_(acc2_h[mt][r]);
                float g2 = sigmoidf_(acc2_g[mt][r]);
                float rw = 0.0f;
#pragma unroll
                for (int ri = 0; ri < RDIM; ++ri) rw += s_rbf[el * 10 + ri] * wfw[ri];
                float eu = h2 * g2 * rw * shw[e * 64 + n];
                if (MODE == 0) {
                    float ef = bf2f(s_inp[el * IST + 64 + n]);
                    out_edge[e * 64 + n] = ef + eu;
                } else {
                    atomicAdd(&agg[dst[e] * 64 + n], eu);
                }
            }
        }
    }
}

// new_node = node_f + agg @ OW, computed in place over the agg buffer (one wave per row)
__global__ __launch_bounds__(256) void finalize_kernel(
    const float* __restrict__ node_f, const float* __restrict__ OW,
    float* __restrict__ out_node, int N)
{
    int w    = (blockIdx.x * 256 + threadIdx.x) >> 6;  // node row
    int lane = threadIdx.x & 63;
    if (w >= N) return;
    float a = out_node[w * 64 + lane];   // this lane's agg element (read before any write)
    float acc = 0.0f;
#pragma unroll
    for (int k = 0; k < 64; ++k) {
        float av = __shfl(a, k, 64);
        acc += av * OW[k * 64 + lane];
    }
    out_node[w * 64 + lane] = node_f[w * 64 + lane] + acc;
}

extern "C" void kernel_launch(void* const* d_in, const int* in_sizes, int n_in,
                              void* d_out, int out_size, void* d_ws, size_t ws_size,
                              hipStream_t stream) {
    const float* node_f = (const float*)d_in[0];
    const float* edge_f = (const float*)d_in[1];
    const int*   src    = (const int*)d_in[2];
    const int*   dst    = (const int*)d_in[3];
    const float* rbf    = (const float*)d_in[4];
    const float* snw    = (const float*)d_in[5];
    const float* sew    = (const float*)d_in[6];
    const float* eW1  = (const float*)d_in[7];
    const float* eb1  = (const float*)d_in[8];
    const float* eW2  = (const float*)d_in[9];
    const float* eb2  = (const float*)d_in[10];
    const float* egW1 = (const float*)d_in[11];
    const float* egb1 = (const float*)d_in[12];
    const float* egW2 = (const float*)d_in[13];
    const float* egb2 = (const float*)d_in[14];
    const float* nW1  = (const float*)d_in[15];
    const float* nb1  = (const float*)d_in[16];
    const float* nW2  = (const float*)d_in[17];
    const float* nb2  = (const float*)d_in[18];
    const float* ngW1 = (const float*)d_in[19];
    const float* ngb1 = (const float*)d_in[20];
    const float* ngW2 = (const float*)d_in[21];
    const float* ngb2 = (const float*)d_in[22];
    const float* noW  = (const float*)d_in[23];
    const float* nwf  = (const float*)d_in[24];
    const float* ewf  = (const float*)d_in[25];

    const int N = in_sizes[0] / 64;
    const int E = in_sizes[1] / 64;

    float* out_node = (float*)d_out;                   // doubles as agg accumulator
    float* out_edge = out_node + (size_t)N * 64;

    // zero the agg region (node section of d_out)
    hipMemsetAsync(out_node, 0, (size_t)N * 64 * sizeof(float), stream);

    const int ntiles = (E + TILE - 1) / TILE;
    const int grid   = ntiles < 2048 ? ntiles : 2048;

    // edge update: new_edge = edge + eu
    mlp_kernel<0><<<grid, 256, 0, stream>>>(
        node_f, edge_f, src, dst, rbf, sew,
        eW1, eb1, eW2, eb2, egW1, egb1, egW2, egb2,
        ewf, out_edge, nullptr, E, ntiles);

    // node messages: atomicAdd into agg (= out_node region)
    mlp_kernel<1><<<grid, 256, 0, stream>>>(
        node_f, out_edge, src, dst, rbf, snw,
        nW1, nb1, nW2, nb2, ngW1, ngb1, ngW2, ngb2,
        nwf, nullptr, out_node, E, ntiles);

    // new_node = node_f + agg @ node_out_W (in place)
    finalize_kernel<<<(N * 64 + 255) / 256, 256, 0, stream>>>(node_f, noW, out_node, N);
}

// Round 2
// 1174.720 us; speedup vs baseline: 1.0718x; 1.0718x over previous
//
#include <hip/hip_runtime.h>
#include <stdint.h>

#define D 64
#define DIN 192
#define RDIM 9
#define TILE 64          // edges per tile
#define IST 200          // inp LDS row stride in bf16 elems (400B: b128-alignable, 2-way banks only)
#define HST 72           // h/g LDS row stride in bf16 elems (144B)

typedef short bf16x8 __attribute__((ext_vector_type(8)));
typedef float f32x4 __attribute__((ext_vector_type(4)));

__device__ __forceinline__ unsigned short f2bf(float f) {
    union { float f; unsigned int u; } v; v.f = f;
    unsigned int r = (v.u + 0x7fffu + ((v.u >> 16) & 1u)) >> 16;  // RNE
    return (unsigned short)r;
}
__device__ __forceinline__ float bf2f(unsigned short h) {
    union { unsigned int u; float f; } v; v.u = ((unsigned int)h) << 16;
    return v.f;
}
__device__ __forceinline__ uint2 pack4bf(float4 x) {
    uint2 r;
    r.x = (unsigned int)f2bf(x.x) | ((unsigned int)f2bf(x.y) << 16);
    r.y = (unsigned int)f2bf(x.z) | ((unsigned int)f2bf(x.w) << 16);
    return r;
}
__device__ __forceinline__ float sigmoidf_(float x) { return 1.0f / (1.0f + __expf(-x)); }
__device__ __forceinline__ float siluf_(float x) { return x * sigmoidf_(x); }
__device__ __forceinline__ f32x4 splat4(float v) { f32x4 r; r[0] = v; r[1] = v; r[2] = v; r[3] = v; return r; }

// MODE 0: edge update -> writes new_edge = edge + eu to out_edge
// MODE 1: node messages -> atomicAdd msg into agg[dst]
template<int MODE>
__global__ __launch_bounds__(256) void mlp_kernel(
    const float* __restrict__ node_f,   // [N,64]
    const float* __restrict__ mid_f,    // [E,64]: edge_features (MODE0) or new_edge (MODE1)
    const int*   __restrict__ src,
    const int*   __restrict__ dst,
    const float* __restrict__ rbf,      // [E,9]
    const float* __restrict__ shw,      // [E,64]
    const float* __restrict__ W1,  const float* __restrict__ b1,
    const float* __restrict__ W2,  const float* __restrict__ b2,
    const float* __restrict__ gW1, const float* __restrict__ gb1,
    const float* __restrict__ gW2, const float* __restrict__ gb2,
    const float* __restrict__ wfW,      // [9,64]
    float* __restrict__ out_edge,
    float* __restrict__ agg,
    int E, int ntiles)
{
    __shared__ __align__(16) unsigned short s_inp[TILE * IST];
    __shared__ __align__(16) unsigned short s_h[TILE * HST];
    __shared__ __align__(16) unsigned short s_g[TILE * HST];
    __shared__ float s_rbf[TILE * 10];

    const int tid  = threadIdx.x;
    const int lane = tid & 63;
    const int wave = tid >> 6;
    const int l15  = lane & 15;
    const int quad = lane >> 4;
    const int n    = wave * 16 + l15;   // output column this lane owns

    // ---- per-wave weight B-fragments in registers (bf16) ----
    bf16x8 w1f[6], gw1f[6], w2f[2], gw2f[2];
#pragma unroll
    for (int kt = 0; kt < 6; ++kt) {
#pragma unroll
        for (int j = 0; j < 8; ++j) {
            int k = kt * 32 + quad * 8 + j;
            w1f[kt][j]  = (short)f2bf(W1[k * 64 + n]);
            gw1f[kt][j] = (short)f2bf(gW1[k * 64 + n]);
        }
    }
#pragma unroll
    for (int kt = 0; kt < 2; ++kt) {
#pragma unroll
        for (int j = 0; j < 8; ++j) {
            int k = kt * 32 + quad * 8 + j;
            w2f[kt][j]  = (short)f2bf(W2[k * 64 + n]);
            gw2f[kt][j] = (short)f2bf(gW2[k * 64 + n]);
        }
    }
    float wfw[RDIM];
#pragma unroll
    for (int r = 0; r < RDIM; ++r) wfw[r] = wfW[r * 64 + n];
    const float b1n = b1[n], b2n = b2[n], gb1n = gb1[n], gb2n = gb2[n];

    for (int tile = blockIdx.x; tile < ntiles; tile += gridDim.x) {
        const int e0 = tile * TILE;
        __syncthreads();   // previous tile's LDS consumers done

        // ---- index load: one coalesced read, broadcast via shfl ----
        int vIdx = 0;
        {
            int p = e0 + (wave << 4) + l15;
            if (p >= E) p = E - 1;
            if (lane < 16)      vIdx = src[p];
            else if (lane < 32) vIdx = dst[p];
        }

        // ---- gather: 12 float4 loads / lane, all in flight, b64 bf16 writes ----
#pragma unroll
        for (int i = 0; i < 4; ++i) {
            const int elq = i * 4 + quad;            // edge-in-wave 0..15
            const int el  = (wave << 4) + elq;       // edge-in-tile
            const int si  = __shfl(vIdx, elq, 64);
            const int di  = __shfl(vIdx, 16 + elq, 64);
            int e  = e0 + el;
            int ec = e < E ? e : E - 1;
            const float4 xi4 = *(const float4*)&node_f[(size_t)si * 64 + l15 * 4];
            const float4 xj4 = *(const float4*)&node_f[(size_t)di * 64 + l15 * 4];
            const float4 ef4 = *(const float4*)&mid_f[(size_t)ec * 64 + l15 * 4];
            *(uint2*)&s_inp[el * IST +       l15 * 4] = pack4bf(xi4);
            *(uint2*)&s_inp[el * IST +  64 + l15 * 4] = pack4bf(ef4);
            *(uint2*)&s_inp[el * IST + 128 + l15 * 4] = pack4bf(xj4);
        }
#pragma unroll
        for (int idx = tid; idx < TILE * RDIM; idx += 256) {
            int gi = e0 * RDIM + idx;
            float v = (gi < E * RDIM) ? rbf[gi] : 0.0f;
            s_rbf[(idx / RDIM) * 10 + (idx % RDIM)] = v;
        }
        __syncthreads();

        // ---- stage 1 ----
        f32x4 acc_h[4], acc_g[4];
#pragma unroll
        for (int mt = 0; mt < 4; ++mt) { acc_h[mt] = splat4(b1n); acc_g[mt] = splat4(gb1n); }
#pragma unroll
        for (int kt = 0; kt < 6; ++kt) {
#pragma unroll
            for (int mt = 0; mt < 4; ++mt) {
                const bf16x8 a = *(const bf16x8*)&s_inp[(mt * 16 + l15) * IST + kt * 32 + quad * 8];
                acc_h[mt] = __builtin_amdgcn_mfma_f32_16x16x32_bf16(a, w1f[kt],  acc_h[mt], 0, 0, 0);
                acc_g[mt] = __builtin_amdgcn_mfma_f32_16x16x32_bf16(a, gw1f[kt], acc_g[mt], 0, 0, 0);
            }
        }
#pragma unroll
        for (int mt = 0; mt < 4; ++mt) {
#pragma unroll
            for (int r = 0; r < 4; ++r) {
                int row = mt * 16 + quad * 4 + r;
                s_h[row * HST + n] = f2bf(siluf_(acc_h[mt][r]));
                s_g[row * HST + n] = f2bf(siluf_(acc_g[mt][r]));
            }
        }
        __syncthreads();

        // ---- stage 2 ----
        f32x4 acc2_h[4], acc2_g[4];
#pragma unroll
        for (int mt = 0; mt < 4; ++mt) { acc2_h[mt] = splat4(b2n); acc2_g[mt] = splat4(gb2n); }
#pragma unroll
        for (int kt = 0; kt < 2; ++kt) {
#pragma unroll
            for (int mt = 0; mt < 4; ++mt) {
                const bf16x8 ah = *(const bf16x8*)&s_h[(mt * 16 + l15) * HST + kt * 32 + quad * 8];
                acc2_h[mt] = __builtin_amdgcn_mfma_f32_16x16x32_bf16(ah, w2f[kt], acc2_h[mt], 0, 0, 0);
                const bf16x8 ag = *(const bf16x8*)&s_g[(mt * 16 + l15) * HST + kt * 32 + quad * 8];
                acc2_g[mt] = __builtin_amdgcn_mfma_f32_16x16x32_bf16(ag, gw2f[kt], acc2_g[mt], 0, 0, 0);
            }
        }

        // ---- epilogue ----
#pragma unroll
        for (int mt = 0; mt < 4; ++mt) {
#pragma unroll
            for (int r = 0; r < 4; ++r) {
                int el = mt * 16 + quad * 4 + r;
                int e  = e0 + el;
                if (e >= E) continue;
                float h2 = siluf_(acc2_h[mt][r]);
                float g2 = sigmoidf_(acc2_g[mt][r]);
                float rw = 0.0f;
#pragma unroll
                for (int ri = 0; ri < RDIM; ++ri) rw += s_rbf[el * 10 + ri] * wfw[ri];
                float eu = h2 * g2 * rw * shw[e * 64 + n];
                if (MODE == 0) {
                    float ef = bf2f(s_inp[el * IST + 64 + n]);
                    out_edge[e * 64 + n] = ef + eu;
                } else {
                    atomicAdd(&agg[dst[e] * 64 + n], eu);
                }
            }
        }
    }
}

// new_node = node_f + agg @ OW via MFMA, in place over the agg buffer (64 rows / block)
__global__ __launch_bounds__(256) void finalize_kernel(
    const float* __restrict__ node_f, const float* __restrict__ OW,
    float* __restrict__ out_node, int N)
{
    __shared__ __align__(16) unsigned short s_a[64 * HST];

    const int tid  = threadIdx.x;
    const int lane = tid & 63;
    const int wave = tid >> 6;
    const int l15  = lane & 15;
    const int quad = lane >> 4;
    const int n    = wave * 16 + l15;
    const int r0   = blockIdx.x * 64;

    bf16x8 owf[2];
#pragma unroll
    for (int kt = 0; kt < 2; ++kt)
#pragma unroll
        for (int j = 0; j < 8; ++j)
            owf[kt][j] = (short)f2bf(OW[(kt * 32 + quad * 8 + j) * 64 + n]);

    // stage agg rows -> bf16 LDS (thread t covers (row = i*16 + t>>4, cols (t&15)*4..+3))
    const int rb = tid >> 4;
    const int cg = (tid & 15) * 4;
#pragma unroll
    for (int i = 0; i < 4; ++i) {
        int row = i * 16 + rb;
        int gr  = r0 + row;
        int grc = gr < N ? gr : N - 1;
        float4 a4 = *(const float4*)&out_node[(size_t)grc * 64 + cg];
        *(uint2*)&s_a[row * HST + cg] = pack4bf(a4);
    }
    __syncthreads();

    f32x4 acc[4];
#pragma unroll
    for (int mt = 0; mt < 4; ++mt) acc[mt] = splat4(0.0f);
#pragma unroll
    for (int kt = 0; kt < 2; ++kt) {
#pragma unroll
        for (int mt = 0; mt < 4; ++mt) {
            const bf16x8 a = *(const bf16x8*)&s_a[(mt * 16 + l15) * HST + kt * 32 + quad * 8];
            acc[mt] = __builtin_amdgcn_mfma_f32_16x16x32_bf16(a, owf[kt], acc[mt], 0, 0, 0);
        }
    }
#pragma unroll
    for (int mt = 0; mt < 4; ++mt) {
#pragma unroll
        for (int r = 0; r < 4; ++r) {
            int gr = r0 + mt * 16 + quad * 4 + r;
            if (gr < N) out_node[(size_t)gr * 64 + n] = node_f[(size_t)gr * 64 + n] + acc[mt][r];
        }
    }
}

extern "C" void kernel_launch(void* const* d_in, const int* in_sizes, int n_in,
                              void* d_out, int out_size, void* d_ws, size_t ws_size,
                              hipStream_t stream) {
    const float* node_f = (const float*)d_in[0];
    const float* edge_f = (const float*)d_in[1];
    const int*   src    = (const int*)d_in[2];
    const int*   dst    = (const int*)d_in[3];
    const float* rbf    = (const float*)d_in[4];
    const float* snw    = (const float*)d_in[5];
    const float* sew    = (const float*)d_in[6];
    const float* eW1  = (const float*)d_in[7];
    const float* eb1  = (const float*)d_in[8];
    const float* eW2  = (const float*)d_in[9];
    const float* eb2  = (const float*)d_in[10];
    const float* egW1 = (const float*)d_in[11];
    const float* egb1 = (const float*)d_in[12];
    const float* egW2 = (const float*)d_in[13];
    const float* egb2 = (const float*)d_in[14];
    const float* nW1  = (const float*)d_in[15];
    const float* nb1  = (const float*)d_in[16];
    const float* nW2  = (const float*)d_in[17];
    const float* nb2  = (const float*)d_in[18];
    const float* ngW1 = (const float*)d_in[19];
    const float* ngb1 = (const float*)d_in[20];
    const float* ngW2 = (const float*)d_in[21];
    const float* ngb2 = (const float*)d_in[22];
    const float* noW  = (const float*)d_in[23];
    const float* nwf  = (const float*)d_in[24];
    const float* ewf  = (const float*)d_in[25];

    const int N = in_sizes[0] / 64;
    const int E = in_sizes[1] / 64;

    float* out_node = (float*)d_out;                   // doubles as agg accumulator
    float* out_edge = out_node + (size_t)N * 64;

    hipMemsetAsync(out_node, 0, (size_t)N * 64 * sizeof(float), stream);

    const int ntiles = (E + TILE - 1) / TILE;
    const int grid   = 768;   // 3 blocks/CU resident, ~10 tiles/block grid-stride

    mlp_kernel<0><<<grid, 256, 0, stream>>>(
        node_f, edge_f, src, dst, rbf, sew,
        eW1, eb1, eW2, eb2, egW1, egb1, egW2, egb2,
        ewf, out_edge, nullptr, E, ntiles);

    mlp_kernel<1><<<grid, 256, 0, stream>>>(
        node_f, out_edge, src, dst, rbf, snw,
        nW1, nb1, nW2, nb2, ngW1, ngb1, ngW2, ngb2,
        nwf, nullptr, out_node, E, ntiles);

    finalize_kernel<<<(N + 63) / 64, 256, 0, stream>>>(node_f, noW, out_node, N);
}